// Round 1
// baseline (912.255 us; speedup 1.0000x reference)
//
#include <hip/hip_runtime.h>
#include <hip/hip_bf16.h>

// C[8192,1000] = sign(X) @ sign(W)^T  via i8 MFMA (values in {-1,0,+1}).
// Pre-pass: W fp32 -> i8 in d_ws, pre-tiled [stage][n(1024)][k'(64)].
// Main: 256 WGs x 512 threads; M_tile=32, full N=1024 (padded) per WG so X
// is read exactly once. X staged fp32->i8 via 2KB LDS per K-stage; W B-frags
// loaded directly global->VGPR (dwordx4) from the pre-tiled ws layout.

#define K_DIM   12288
#define N_CLS   1000
#define N_PAD   1024
#define K_TILE  64
#define STAGES  (K_DIM / K_TILE)        // 192
#define STAGE_BYTES (N_PAD * K_TILE)    // 65536

typedef int int4v __attribute__((ext_vector_type(4)));

// sign byte: +1 / -1 / 0 (handles +-0.0 exactly)
__device__ __forceinline__ unsigned sign_byte(unsigned bits) {
    unsigned mag = bits & 0x7fffffffu;
    unsigned nz = mag ? 1u : 0u;        // 0 if value is +-0.0
    int sgn = ((int)bits) >> 31;        // 0 or -1
    int v = (((int)nz) ^ sgn) - sgn;    // +1, -1, or 0
    return (unsigned)(v & 0xff);
}

__device__ __forceinline__ unsigned pack4(uint4 b) {
    return sign_byte(b.x) | (sign_byte(b.y) << 8) |
           (sign_byte(b.z) << 16) | (sign_byte(b.w) << 24);
}

// ---- pre-pass: W[1000][12288] fp32 -> ws[stage][n][64] i8 (rows >=1000 zeroed)
__global__ void pack_w_kernel(const float* __restrict__ w,
                              unsigned char* __restrict__ ws) {
    int gid = blockIdx.x * 256 + threadIdx.x;   // one thread per output dword
    int n = gid / (K_DIM / 4);                  // 0..1023
    int d = gid % (K_DIM / 4);
    int k = d * 4;
    int stage = k >> 6;
    unsigned outw = 0;
    if (n < N_CLS) {
        uint4 b = *reinterpret_cast<const uint4*>(w + (size_t)n * K_DIM + k);
        outw = pack4(b);
    }
    *reinterpret_cast<unsigned*>(ws + (size_t)stage * STAGE_BYTES + n * K_TILE + (k & 63)) = outw;
}

// ---- main GEMM
__global__ __launch_bounds__(512, 2)
void bgemm_kernel(const float* __restrict__ x,
                  const unsigned char* __restrict__ wq,
                  float* __restrict__ out) {
    __shared__ unsigned x_lds[32 * 16];         // 32 rows x 64 i8 bytes

    const int tid  = threadIdx.x;
    const int wave = tid >> 6;
    const int lane = tid & 63;
    const int m0   = blockIdx.x * 32;
    const int q    = lane >> 4;                 // 0..3 (k-quadrant)
    const int l15  = lane & 15;
    const int nbase = wave * 128;               // wave's N-chunk

    int4v acc[2][8];
#pragma unroll
    for (int i = 0; i < 2; ++i)
#pragma unroll
        for (int j = 0; j < 8; ++j)
            acc[i][j] = (int4v){0, 0, 0, 0};

    // staging mapping: thread t loads 4 fp32 of row (t>>4), k-offset (t&15)*4
    const int srow = tid >> 4;                  // 0..31
    const int skq  = (tid & 15) * 4;            // 0..60
    const float* xrow = x + (size_t)(m0 + srow) * K_DIM + skq;
    const int lds_widx = srow * 16 + (skq >> 2);

    for (int s = 0; s < STAGES; ++s) {
        __syncthreads();                        // protect LDS from prior reads
        {
            uint4 b = *reinterpret_cast<const uint4*>(xrow + s * K_TILE);
            x_lds[lds_widx] = pack4(b);
        }
        __syncthreads();

        int4v a[2];
#pragma unroll
        for (int mt = 0; mt < 2; ++mt)
            a[mt] = *reinterpret_cast<const int4v*>(&x_lds[(mt * 16 + l15) * 16 + q * 4]);

        const unsigned char* wp = wq + (size_t)s * STAGE_BYTES + (nbase + l15) * K_TILE + q * 16;
#pragma unroll
        for (int nt = 0; nt < 8; ++nt) {
            int4v b = *reinterpret_cast<const int4v*>(wp + nt * 16 * K_TILE);
            acc[0][nt] = __builtin_amdgcn_mfma_i32_16x16x64_i8(a[0], b, acc[0][nt], 0, 0, 0);
            acc[1][nt] = __builtin_amdgcn_mfma_i32_16x16x64_i8(a[1], b, acc[1][nt], 0, 0, 0);
        }
    }

    // epilogue: D col = l15 (N), row = q*4 + reg (M)
#pragma unroll
    for (int mt = 0; mt < 2; ++mt) {
#pragma unroll
        for (int nt = 0; nt < 8; ++nt) {
            int col = nbase + nt * 16 + l15;
            if (col < N_CLS) {
#pragma unroll
                for (int r = 0; r < 4; ++r) {
                    int row = m0 + mt * 16 + q * 4 + r;
                    out[(size_t)row * N_CLS + col] = (float)acc[mt][nt][r];
                }
            }
        }
    }
}

extern "C" void kernel_launch(void* const* d_in, const int* in_sizes, int n_in,
                              void* d_out, int out_size, void* d_ws, size_t ws_size,
                              hipStream_t stream) {
    const float* x = (const float*)d_in[0];     // [8192, 12288]
    const float* w = (const float*)d_in[1];     // [1000, 12288]
    float* out = (float*)d_out;                 // [8192, 1000]
    unsigned char* ws = (unsigned char*)d_ws;   // needs 12.6 MB

    // pre-pass: 1024*3072 dwords / 256 threads = 12288 blocks
    pack_w_kernel<<<(N_PAD * (K_DIM / 4)) / 256, 256, 0, stream>>>(w, ws);

    // main: 8192/32 = 256 workgroups
    bgemm_kernel<<<8192 / 32, 512, 0, stream>>>(x, ws, out);
}

// Round 3
// 661.046 us; speedup vs baseline: 1.3800x; 1.3800x over previous
//
#include <hip/hip_runtime.h>
#include <hip/hip_bf16.h>

// C[8192,1000] = sign(X) @ sign(W)^T via i8 MFMA (values in {-1,0,+1}).
// pack_w: W fp32 -> i8, pre-tiled [stage][n(1024)][64B] in d_ws.
// bgemm: 256 WGs = 128 M-tiles(64 rows) x split-K 2. Per WG: 8 waves x N=128,
//   K-chunk = 128 (2 stages) per barrier, register-prefetched X staging into
//   XOR-swizzled double-buffered LDS, B frags direct global->VGPR from L2.
// Split-K partials: i16 halves of one dword in ws (disjoint bytes, no race),
//   reduce kernel sums -> float out. Fallback: zero + atomicAdd if ws small.

#define K_DIM   12288
#define N_CLS   1000
#define N_PAD   1024
#define KSPLIT  2
#define K_HALF  (K_DIM / KSPLIT)         // 6144
#define STAGE_BYTES (N_PAD * 64)         // 65536
#define N_STAGE_TOT (K_DIM / 64)         // 192
#define CHUNK_STAGES 2
#define CHUNK_K  (CHUNK_STAGES * 64)     // 128
#define CHUNKS   (K_HALF / CHUNK_K)      // 48
#define M_TILE   64
#define B_ROWS   8192
#define WS_W_BYTES ((size_t)N_STAGE_TOT * STAGE_BYTES)     // 12,582,912
#define WS_P_BYTES ((size_t)B_ROWS * N_CLS * 4)            // 32,768,000

typedef int int4v __attribute__((ext_vector_type(4)));
typedef unsigned int uint4v __attribute__((ext_vector_type(4)));

// sign byte: +1 / -1 / 0 (handles +-0.0 exactly)
__device__ __forceinline__ unsigned sign_byte(unsigned bits) {
    unsigned mag = bits & 0x7fffffffu;
    unsigned nz = mag ? 1u : 0u;
    int sgn = ((int)bits) >> 31;
    int v = (((int)nz) ^ sgn) - sgn;
    return (unsigned)(v & 0xff);
}

__device__ __forceinline__ unsigned pack4(uint4v b) {
    return sign_byte(b.x) | (sign_byte(b.y) << 8) |
           (sign_byte(b.z) << 16) | (sign_byte(b.w) << 24);
}

// ---- W pre-pass: one thread -> 16 consecutive packed bytes of (stage, n).
// Wave writes 1 KB contiguous (16 n-rows x 64 B of one stage).
__global__ void pack_w_kernel(const float* __restrict__ w,
                              unsigned char* __restrict__ ws) {
    const int gid = blockIdx.x * 256 + threadIdx.x;   // 786432 total
    const int stage = gid >> 12;                      // 0..191
    const int n = (gid >> 2) & 1023;
    const int q16 = gid & 3;
    const int k = stage * 64 + q16 * 16;
    uint4v o = {0u, 0u, 0u, 0u};
    if (n < N_CLS) {
        const float* p = w + (size_t)n * K_DIM + k;
        o.x = pack4(*reinterpret_cast<const uint4v*>(p));
        o.y = pack4(*reinterpret_cast<const uint4v*>(p + 4));
        o.z = pack4(*reinterpret_cast<const uint4v*>(p + 8));
        o.w = pack4(*reinterpret_cast<const uint4v*>(p + 12));
    }
    *reinterpret_cast<uint4v*>(ws + (size_t)stage * STAGE_BYTES + n * 64 + q16 * 16) = o;
}

__global__ void zero_kernel(float* __restrict__ out) {
    const int i = blockIdx.x * 256 + threadIdx.x;     // 2,048,000 float4
    float4 z = {0.f, 0.f, 0.f, 0.f};
    *reinterpret_cast<float4*>(out + (size_t)i * 4) = z;
}

__global__ void reduce_kernel(const unsigned* __restrict__ part,
                              float* __restrict__ out) {
    const int i = blockIdx.x * 256 + threadIdx.x;     // 2,048,000 uint4
    uint4v w = *reinterpret_cast<const uint4v*>(part + (size_t)i * 4);
    float4 f;
    f.x = (float)((int)(short)(w.x & 0xffffu) + (int)(short)(w.x >> 16));
    f.y = (float)((int)(short)(w.y & 0xffffu) + (int)(short)(w.y >> 16));
    f.z = (float)((int)(short)(w.z & 0xffffu) + (int)(short)(w.z >> 16));
    f.w = (float)((int)(short)(w.w & 0xffffu) + (int)(short)(w.w >> 16));
    *reinterpret_cast<float4*>(out + (size_t)i * 4) = f;
}

// ---- main GEMM
template<int USE_PARTIAL>
__global__ __launch_bounds__(512, 2)
void bgemm_kernel(const float* __restrict__ x,
                  const unsigned char* __restrict__ wq,
                  unsigned* __restrict__ part,
                  float* __restrict__ out) {
    // 2 buffers x 64 rows x 32 dwords (128 i8 per row), XOR-swizzled
    __shared__ unsigned x_lds[2][M_TILE * 32];

    const int tid  = threadIdx.x;
    const int wave = tid >> 6;
    const int lane = tid & 63;
    const int q    = lane >> 4;
    const int l15  = lane & 15;
    const int bx   = blockIdx.x;
    const int mtile = bx >> 1;
    const int kh    = bx & 1;
    const int m0    = mtile * M_TILE;
    const int nbase = wave * 128;

    int4v acc[4][8];
#pragma unroll
    for (int i = 0; i < 4; ++i)
#pragma unroll
        for (int j = 0; j < 8; ++j)
            acc[i][j] = (int4v){0, 0, 0, 0};

    // staging: thread t -> row t>>3; i-th uint4 covers logical dword i*8+(t&7)
    const int srow = tid >> 3;
    const int scol = tid & 7;
    const float* xp = x + (size_t)(m0 + srow) * K_DIM + kh * K_HALF + scol * 4;
    const int sw_w = (srow & 3) * 8;

    const unsigned char* wqb = wq + (size_t)(kh * (N_STAGE_TOT / KSPLIT)) * STAGE_BYTES
                               + (nbase + l15) * 64 + q * 16;
    const int rsw = (l15 & 3) * 8;

    uint4v xr[4];
#pragma unroll
    for (int i = 0; i < 4; ++i)
        xr[i] = __builtin_nontemporal_load(reinterpret_cast<const uint4v*>(xp + i * 32));
#pragma unroll
    for (int i = 0; i < 4; ++i)
        x_lds[0][srow * 32 + (((i * 8 + scol)) ^ sw_w)] = pack4(xr[i]);
    __syncthreads();

#pragma unroll 2
    for (int c = 0; c < CHUNKS; ++c) {
        const int cur = c & 1;
        if (c + 1 < CHUNKS) {
            const float* xpc = xp + (size_t)(c + 1) * CHUNK_K;
#pragma unroll
            for (int i = 0; i < 4; ++i)
                xr[i] = __builtin_nontemporal_load(reinterpret_cast<const uint4v*>(xpc + i * 32));
        }
        const unsigned char* wpc = wqb + (size_t)(c * CHUNK_STAGES) * STAGE_BYTES;
#pragma unroll
        for (int st = 0; st < CHUNK_STAGES; ++st) {
            int4v a[4];
#pragma unroll
            for (int mt = 0; mt < 4; ++mt)
                a[mt] = *reinterpret_cast<const int4v*>(
                    &x_lds[cur][(mt * 16 + l15) * 32 + ((st * 16 + q * 4) ^ rsw)]);
            const unsigned char* wp = wpc + st * STAGE_BYTES;
#pragma unroll
            for (int nt = 0; nt < 8; ++nt) {
                int4v b = *reinterpret_cast<const int4v*>(wp + nt * 1024);
#pragma unroll
                for (int mt = 0; mt < 4; ++mt)
                    acc[mt][nt] = __builtin_amdgcn_mfma_i32_16x16x64_i8(a[mt], b, acc[mt][nt], 0, 0, 0);
            }
        }
        if (c + 1 < CHUNKS) {
#pragma unroll
            for (int i = 0; i < 4; ++i)
                x_lds[cur ^ 1][srow * 32 + (((i * 8 + scol)) ^ sw_w)] = pack4(xr[i]);
        }
        __syncthreads();
    }

    // epilogue: D col(N) = l15 offset, row(M) = q*4 + reg
#pragma unroll
    for (int mt = 0; mt < 4; ++mt) {
#pragma unroll
        for (int nt = 0; nt < 8; ++nt) {
            const int col = nbase + nt * 16 + l15;
            if (col < N_CLS) {
#pragma unroll
                for (int r = 0; r < 4; ++r) {
                    const int row = m0 + mt * 16 + q * 4 + r;
                    const size_t idx = (size_t)row * N_CLS + col;
                    if (USE_PARTIAL) {
                        reinterpret_cast<short*>(part)[idx * 2 + kh] = (short)acc[mt][nt][r];
                    } else {
                        atomicAdd(&out[idx], (float)acc[mt][nt][r]);
                    }
                }
            }
        }
    }
}

extern "C" void kernel_launch(void* const* d_in, const int* in_sizes, int n_in,
                              void* d_out, int out_size, void* d_ws, size_t ws_size,
                              hipStream_t stream) {
    const float* x = (const float*)d_in[0];     // [8192, 12288]
    const float* w = (const float*)d_in[1];     // [1000, 12288]
    float* out = (float*)d_out;                 // [8192, 1000]
    unsigned char* ws = (unsigned char*)d_ws;

    pack_w_kernel<<<3072, 256, 0, stream>>>(w, ws);

    unsigned* part = reinterpret_cast<unsigned*>(ws + WS_W_BYTES);
    const bool use_part = ws_size >= WS_W_BYTES + WS_P_BYTES;
    if (use_part) {
        bgemm_kernel<1><<<256, 512, 0, stream>>>(x, ws, part, out);
        reduce_kernel<<<(B_ROWS * N_CLS) / (4 * 256), 256, 0, stream>>>(part, out);
    } else {
        zero_kernel<<<(B_ROWS * N_CLS) / (4 * 256), 256, 0, stream>>>(out);
        bgemm_kernel<0><<<256, 512, 0, stream>>>(x, ws, part, out);
    }
}